// Round 14
// baseline (1320.231 us; speedup 1.0000x reference)
//
#include <hip/hip_runtime.h>
#include <math.h>

#define BB 16
#define TT 16
#define KK 4
#define VV 10003
#define DD 256
#define CC 64
#define NTILE 40        // ceil(V/256) v-tiles
#define RPB 16          // rows per k_gemm block
#define VP 10016        // padded row stride for logits scratch
#define FNEG (-1e30f)

// ---------- top-4 list, f32 keys (tie-break: lower index wins) ----------
struct L4 { float v[4]; int ix[4]; };

__device__ __forceinline__ void l4_init(L4 &l) {
#pragma unroll
  for (int j = 0; j < 4; ++j) { l.v[j] = FNEG; l.ix[j] = 0x7fffffff; }
}
__device__ __forceinline__ bool better(float v, int ix, float v2, int ix2) {
  return (v > v2) || (v == v2 && ix < ix2);
}
__device__ __forceinline__ void l4_insert(L4 &l, float v, int ix) {
  if (!better(v, ix, l.v[3], l.ix[3])) return;
  int p = 3;
  while (p > 0 && better(v, ix, l.v[p-1], l.ix[p-1])) {
    l.v[p] = l.v[p-1]; l.ix[p] = l.ix[p-1]; --p;
  }
  l.v[p] = v; l.ix[p] = ix;
}
__device__ __forceinline__ void l4_merge(L4 &a, const L4 &b) {
  L4 r; int ia = 0, ib = 0;
#pragma unroll
  for (int j = 0; j < 4; ++j) {
    if (better(a.v[ia], a.ix[ia], b.v[ib], b.ix[ib])) {
      r.v[j] = a.v[ia]; r.ix[j] = a.ix[ia]; ++ia;
    } else {
      r.v[j] = b.v[ib]; r.ix[j] = b.ix[ib]; ++ib;
    }
  }
  a = r;
}

// ---------- numpy pairwise_sum base case (8 <= n <= 128) — bit-exact ----------
__device__ float np_block_sum(const float* a, int n) {
  float r0=a[0],r1=a[1],r2=a[2],r3=a[3],r4=a[4],r5=a[5],r6=a[6],r7=a[7];
  int i;
  for (i = 8; i + 8 <= n; i += 8) {
    r0 += a[i+0]; r1 += a[i+1]; r2 += a[i+2]; r3 += a[i+3];
    r4 += a[i+4]; r5 += a[i+5]; r6 += a[i+6]; r7 += a[i+7];
  }
  float res = ((r0 + r1) + (r2 + r3)) + ((r4 + r5) + (r6 + r7));
  for (; i < n; ++i) res += a[i];
  return res;
}

// ---------- kernel 0: init chain ----------
__global__ void k_init(const int* __restrict__ loc_tar, int* __restrict__ chainA) {
  int t = threadIdx.x;            // 256 = B*T
  int b = t >> 4, j = t & 15;
  chainA[t] = (j == 0) ? loc_tar[b * TT] : 0;
}

// ---------- kernel 1: sgemm-mimic logits, double-buffered register prefetch ---
// R13 post-mortem: unroll-8 compiled to load->vmcnt(0)->compute per group,
// zero overlap => latency-bound at 45us. Fix: manual 2-stage pipeline — load
// w-group g+1 into wb[] (independent) while computing group g from wa[], so
// the 512 FMA cycles overlap the ~1000-cycle fabric latency. Compute order
// per accumulator is still strictly d-ascending fmaf => bit-exact vs R7-R13.
__global__ __launch_bounds__(256)
void k_gemm(const float* __restrict__ E, const float* __restrict__ zs,
            const float* __restrict__ Wv, const float* __restrict__ bv,
            const int* __restrict__ chain, float* __restrict__ Lg,
            int step, int N, int Mshift) {
  __shared__ float xs[RPB * DD];     // 16 KB  (h rows, broadcast-read)
  __shared__ int cs[RPB];

  const int t = threadIdx.x;
  const int tile = blockIdx.x % NTILE;        // tile-major => XCD affinity
  const int n0 = (blockIdx.x / NTILE) * RPB;
  const int v0 = tile * 256;
  const int v = v0 + t;
  const int vok = (v < VV);
  const int vc = vok ? v : (VV - 1);

  if (t < RPB) {
    int n = n0 + t;
    int c = (n < N) ? chain[n * TT + step] : 0;
    if ((unsigned)c >= VV) c = 0;    // defensive
    cs[t] = c;
  }
  __syncthreads();

  // stage xs rows: h = E[c] + zs[b]  (single f32 add, np order)
  for (int e = t; e < RPB * DD; e += 256) {
    int r = e >> 8, d = e & 255;
    int n = n0 + r;
    int b = (n < N) ? (n >> Mshift) : 0;
    xs[e] = E[cs[r] * DD + d] + zs[b * DD + d];
  }
  __syncthreads();

  float acc[RPB];
#pragma unroll
  for (int r = 0; r < RPB; ++r) acc[r] = 0.f;

  const float* wp = Wv + vc;

  float wa[32], wb[32];
#pragma unroll
  for (int u = 0; u < 32; ++u) wa[u] = wp[(size_t)u * VV];   // group 0

  for (int g = 0; g < 8; ++g) {
    const int d0 = g * 32;
    if (g < 7) {
#pragma unroll
      for (int u = 0; u < 32; ++u) wb[u] = wp[(size_t)(d0 + 32 + u) * VV];
    }
    // compute current group (d ascending — exact chain order preserved)
#pragma unroll
    for (int u = 0; u < 32; ++u) {
      const int d = d0 + u;
#pragma unroll
      for (int r = 0; r < RPB; ++r) acc[r] = fmaf(xs[r * DD + d], wa[u], acc[r]);
    }
#pragma unroll
    for (int u = 0; u < 32; ++u) wa[u] = wb[u];
  }

  if (vok) {
    const float bvv = bv[v];
#pragma unroll
    for (int r = 0; r < RPB; ++r) {
      int n = n0 + r;
      if (n < N) Lg[(size_t)n * VP + v] = acc[r] + bvv;   // bias after gemm (np)
    }
  }
}

// ---------- kernel 2: np-exact max/top4/pairwise-lse, parallel (UNCHANGED) ----
__global__ __launch_bounds__(256)
void k_red(const float* __restrict__ Lg, float* __restrict__ topP,
           int* __restrict__ topI) {
  __shared__ float row[VV];          // 40012 B (logits, then exp'd values)
  __shared__ float pm[256];
  __shared__ float pv4[256 * 4];
  __shared__ int   pi4[256 * 4];
  __shared__ int   segBase[255];     // heap: node -> segment start
  __shared__ int   segN[255];        // heap: node -> segment size
  __shared__ float val[255];         // heap: node -> pairwise sum

  const int n = blockIdx.x;
  const int t = threadIdx.x;
  const float* grow = Lg + (size_t)n * VP;

  for (int v = t; v < VV; v += 256) row[v] = grow[v];

  if (t == 0) { segBase[0] = 0; segN[0] = VV; }
  __syncthreads();
  for (int L = 0; L < 7; ++L) {
    int first = (1 << L) - 1, cnt = 1 << L;
    if (t < cnt) {
      int p = first + t;
      int np_ = segN[p], bp = segBase[p];
      int n2 = np_ / 2; n2 -= n2 % 8;
      segBase[2 * p + 1] = bp;       segN[2 * p + 1] = n2;
      segBase[2 * p + 2] = bp + n2;  segN[2 * p + 2] = np_ - n2;
    }
    __syncthreads();
  }

  float m = FNEG;
  L4 top; l4_init(top);
  for (int v = t; v < VV; v += 256) {
    float x = row[v];
    if (x > m) m = x;
    l4_insert(top, x, v);
  }
  pm[t] = m;
#pragma unroll
  for (int j = 0; j < 4; ++j) { pv4[t * 4 + j] = top.v[j]; pi4[t * 4 + j] = top.ix[j]; }
  __syncthreads();

  for (int str = 128; str >= 1; str >>= 1) {
    if (t < str) {
      if (pm[t + str] > pm[t]) pm[t] = pm[t + str];
      L4 a, b;
#pragma unroll
      for (int j = 0; j < 4; ++j) {
        a.v[j] = pv4[t * 4 + j];          a.ix[j] = pi4[t * 4 + j];
        b.v[j] = pv4[(t + str) * 4 + j];  b.ix[j] = pi4[(t + str) * 4 + j];
      }
      l4_merge(a, b);
#pragma unroll
      for (int j = 0; j < 4; ++j) { pv4[t * 4 + j] = a.v[j]; pi4[t * 4 + j] = a.ix[j]; }
    }
    __syncthreads();
  }
  const float gm = pm[0];

  for (int v = t; v < VV; v += 256)
    row[v] = (float)exp((double)(row[v] - gm));
  __syncthreads();

  if (t < 128) {
    int nd = 127 + t;
    val[nd] = np_block_sum(&row[segBase[nd]], segN[nd]);
  }
  __syncthreads();

  for (int L = 6; L >= 0; --L) {
    int first = (1 << L) - 1, cnt = 1 << L;
    if (t < cnt) {
      int p = first + t;
      val[p] = val[2 * p + 1] + val[2 * p + 2];
    }
    __syncthreads();
  }

  if (t == 0) {
    float ls = (float)log((double)val[0]);
#pragma unroll
    for (int j = 0; j < 4; ++j) {
      topP[n * 4 + j] = (pv4[j] - gm) - ls;   // (x - m) - log(s), two f32 subs
      topI[n * 4 + j] = pi4[j];
    }
  }
}

// ---------- kernel 3: beam update, wave-parallel (UNCHANGED) ----------
__global__ __launch_bounds__(512)
void k_beam(const float* __restrict__ topP, const int* __restrict__ topI,
            float* __restrict__ prob, const int* __restrict__ chain_cur,
            int* __restrict__ chain_next, int step) {
  __shared__ int sel_src[BB][8];
  __shared__ int sel_tok[BB][8];

  const int tid = threadIdx.x;
  const int b = tid >> 5;      // batch 0..15
  const int c = tid & 31;      // candidate 0..31

  if (step == 0) {
    for (int e = tid; e < BB * KK * TT; e += 512) {
      int dst = e >> 4, q = e & 15;
      int bb = dst >> 2, kk = dst & 3;
      int val;
      if (q == 1) {
        int tok = topI[bb * 4 + kk]; if ((unsigned)tok >= VV) tok = 0;
        val = tok;
      } else {
        val = chain_cur[bb * TT + q];
      }
      chain_next[dst * TT + q] = val;
    }
    if (tid < BB * KK) {
      int bb = tid >> 2, kk = tid & 3;
      prob[bb * 8 + kk] = topP[bb * 4 + kk];
    }
    return;
  }

  const int M = (step == 1) ? 4 : 8;
  const int nc = M * 4;

  float act;
  if (c < nc) {
    int m = c >> 2, k = c & 3;
    act = prob[b * 8 + m] * topP[(b * M + m) * 4 + k];
  } else {
    act = -INFINITY;
  }

  for (int j = 0; j < 8; ++j) {
    float rv = act; int ri = c;
#pragma unroll
    for (int off = 1; off < 32; off <<= 1) {
      float v2 = __shfl_xor(rv, off, 32);
      int   i2 = __shfl_xor(ri, off, 32);
      if (v2 > rv || (v2 == rv && i2 < ri)) { rv = v2; ri = i2; }
    }
    if (c == ri) act = -INFINITY;          // mark used
    if (c == 0) {
      int m = ri >> 2, k = ri & 3;
      int src = b * M + m;
      int tok = topI[src * 4 + k]; if ((unsigned)tok >= VV) tok = 0;
      sel_src[b][j] = src;
      sel_tok[b][j] = tok;
      prob[b * 8 + j] = rv;
    }
  }
  __syncthreads();

  for (int e = tid; e < BB * 8 * TT; e += 512) {
    int dst = e >> 4, q = e & 15;
    int bb = dst >> 3, j = dst & 7;
    int src = sel_src[bb][j];
    int val = (q == step + 1) ? sel_tok[bb][j] : chain_cur[src * TT + q];
    chain_next[dst * TT + q] = val;
  }
}

// ---------- kernel 4: finalize: loc_chain + tim_chain (UNCHANGED) ----------
__global__ __launch_bounds__(64)
void k_final(const int* __restrict__ chain, const float* __restrict__ E,
             const float* __restrict__ Wc, const float* __restrict__ bc,
             const float* __restrict__ Wt, const float* __restrict__ zt,
             const float* __restrict__ Wzt, float* __restrict__ out) {
  int blk = blockIdx.x;           // 224 = B*(T-2)
  int b = blk / (TT - 2), t = blk % (TT - 2);
  int lane = threadIdx.x;         // 64 = C
  int loc = chain[(b * 8) * TT + 1 + t];   // best beam, positions 1..T-2
  if ((unsigned)loc >= VV) loc = 0;        // defensive
  double acc = (double)bc[lane];
  const float* er = E + loc * DD;
  for (int d = 0; d < DD; ++d) acc += (double)er[d] * (double)Wc[d * CC + lane];
  double val = tanh(acc) * (double)Wt[lane];
  const float* ztr = zt + b * DD;
#pragma unroll
  for (int q = 0; q < 4; ++q) val += (double)ztr[lane * 4 + q] * (double)Wzt[lane * 4 + q];
  for (int off = 32; off; off >>= 1) val += __shfl_down(val, off);
  if (lane == 0) {
    out[b * (TT - 2) + t] = (float)loc;                 // loc_chain as float
    out[BB * (TT - 2) + b * (TT - 2) + t] = (float)val; // tim_chain
  }
}

// ---------- host ----------
extern "C" void kernel_launch(void* const* d_in, const int* in_sizes, int n_in,
                              void* d_out, int out_size, void* d_ws, size_t ws_size,
                              hipStream_t stream) {
  const int*   loc_tar = (const int*)  d_in[0];
  const float* zs      = (const float*)d_in[1];
  const float* zt      = (const float*)d_in[2];
  const float* E       = (const float*)d_in[3];
  const float* Wv      = (const float*)d_in[4];
  const float* bv      = (const float*)d_in[5];
  const float* Wc      = (const float*)d_in[6];
  const float* bc      = (const float*)d_in[7];
  const float* Wt      = (const float*)d_in[8];
  const float* Wzt     = (const float*)d_in[9];
  float* out = (float*)d_out;

  char* w = (char*)d_ws;
  float* Lg     = (float*)(w);                   // 128*10016*4 = 5,128,192 B
  float* topP   = (float*)(w + 5128192);         // 512 f32 = 2048 B
  int*   topI   = (int*)  (w + 5130240);         // 512 int = 2048 B
  float* prob   = (float*)(w + 5132288);         // 128 f32 = 512 B
  int*   chainA = (int*)  (w + 5132800);         // 2048 int = 8192 B
  int*   chainB = (int*)  (w + 5140992);         // 2048 int = 8192 B

  k_init<<<1, 256, 0, stream>>>(loc_tar, chainA);

  int N = BB;
  int* cur = chainA;
  int* nxt = chainB;
  for (int i = 0; i < TT - 1; ++i) {
    int Mshift = (i == 0) ? 0 : ((i == 1) ? 2 : 3);
    int ntn = (N + RPB - 1) / RPB;
    k_gemm<<<ntn * NTILE, 256, 0, stream>>>(E, zs, Wv, bv, cur, Lg, i, N, Mshift);
    k_red<<<N, 256, 0, stream>>>(Lg, topP, topI);
    k_beam<<<1, 512, 0, stream>>>(topP, topI, prob, cur, nxt, i);
    int* t2 = cur; cur = nxt; nxt = t2;
    N = (i == 0) ? BB * KK : BB * 2 * KK;
  }

  k_final<<<BB * (TT - 2), 64, 0, stream>>>(cur, E, Wc, bc, Wt, zt, Wzt, out);
}